// Round 5
// baseline (8337.603 us; speedup 1.0000x reference)
//
#include <hip/hip_runtime.h>
#include <hip/hip_bf16.h>
#include <cstdint>

#define B 2048
#define NL 32
#define FEAT 512
#define HID 512
#define HW 64
#define OUTSZ 42
#define G3 1536
#define LDIH 554   // gru_w_ih row stride
#define KC 576     // K for ghss GEMM: 512 h + 42 ss + 22 pad
#define NBG 8      // batch groups
#define BGR 256    // rows per batch group
#define NPB 32     // blocks per batch group

typedef __bf16 bf16x8 __attribute__((ext_vector_type(8)));
typedef unsigned short u16x8 __attribute__((ext_vector_type(8)));
typedef float f32x4 __attribute__((ext_vector_type(4)));
typedef __hip_bfloat16 bf16_t;

#define MFMA(a,b,c) __builtin_amdgcn_mfma_f32_16x16x32_bf16(a,b,c,0,0,0)

static __device__ __forceinline__ float sigmoidf_(float x){ return 1.f/(1.f+__expf(-x)); }

// ---------------- one-time weight prep ----------------
// w_perm [1536][576]: row p: ng=p/48, u=p%48, g=u/16, jl=u%16 -> orig = g*512 + ng*16 + jl.
//   cols 0..511 = w_hh[orig]; 512..553 = w_ih ss-cols (r/z gates only, zero for n); rest 0.
// w_ssn [512][64]: n-gate input-side ss weights (w_ih rows 1024+j, cols 512..553), padded.
// lin1_wb [512][512]; lin2_wp [48][512] (rows 42..47 zero); w_ih512b [1536][512];
// bias_comb [1536] = b_ih + (gate<2 ? b_hh : 0).
__global__ __launch_bounds__(256) void prep2_kernel(
    const float* __restrict__ w_ih, const float* __restrict__ w_hh,
    const float* __restrict__ lin1_w, const float* __restrict__ lin2_w,
    const float* __restrict__ b_ih, const float* __restrict__ b_hh,
    bf16_t* __restrict__ w_perm, bf16_t* __restrict__ w_ssn,
    bf16_t* __restrict__ lin1_wb, bf16_t* __restrict__ lin2_wp,
    bf16_t* __restrict__ w_ih512b, float* __restrict__ bias_comb){
  const int NP = G3*KC, NS = 512*64, NL1 = 512*512, NL2 = 48*512, NI = G3*512, NB = G3;
  const int total = NP+NS+NL1+NL2+NI+NB;
  for (int idx = blockIdx.x*256 + threadIdx.x; idx < total; idx += gridDim.x*256){
    int i = idx;
    if (i < NP){
      int p = i / KC, k = i % KC;
      int ng = p / 48, u = p % 48, g = u >> 4, jl = u & 15;
      int orig = g*512 + ng*16 + jl;
      float v = (k < 512) ? w_hh[orig*512 + k]
              : ((k < 512 + OUTSZ && g < 2) ? w_ih[(size_t)orig*LDIH + k] : 0.f);
      w_perm[i] = __float2bfloat16(v);
    } else if ((i -= NP) < NS){
      int j = i >> 6, k = i & 63;
      float v = (k < OUTSZ) ? w_ih[(size_t)(1024+j)*LDIH + 512 + k] : 0.f;
      w_ssn[i] = __float2bfloat16(v);
    } else if ((i -= NS) < NL1){
      lin1_wb[i] = __float2bfloat16(lin1_w[i]);
    } else if ((i -= NL1) < NL2){
      int j = i >> 9, k = i & 511;
      lin2_wp[i] = __float2bfloat16(j < OUTSZ ? lin2_w[j*512 + k] : 0.f);
    } else if ((i -= NL2) < NI){
      int r = i >> 9, c = i & 511;
      w_ih512b[i] = __float2bfloat16(w_ih[(size_t)r*LDIH + c]);
    } else {
      int j = i - NI;
      bias_comb[j] = b_ih[j] + (j < 1024 ? b_hh[j] : 0.f);
    }
  }
}

// ---------------- attention precompute (step-invariant) ----------------
__global__ __launch_bounds__(256) void att_kernel(const float* __restrict__ feat,
                                                  const float* __restrict__ att_w,
                                                  bf16_t* __restrict__ att_feat){
  int b = blockIdx.x;
  const float* fb = feat + (size_t)b * FEAT * HW;
  __shared__ float part[4][64];
  __shared__ float attv[64];
  int t = threadIdx.x;
  int s = t & 63, q = t >> 6;
  float acc = 0.f;
  for (int c = q*128; c < q*128 + 128; ++c)
    acc = fmaf(fb[c*HW + s], att_w[c], acc);
  part[q][s] = acc;
  __syncthreads();
  if (t < 64){
    float v = part[0][t] + part[1][t] + part[2][t] + part[3][t];
    float m = v;
    for (int o = 32; o > 0; o >>= 1) m = fmaxf(m, __shfl_xor(m, o));
    float e = __expf(v - m);
    float ssum = e;
    for (int o = 32; o > 0; o >>= 1) ssum += __shfl_xor(ssum, o);
    attv[t] = e / ssum * 2.0f;   // * BETA
  }
  __syncthreads();
  for (int c = t; c < FEAT; c += 256){
    const float4* row = (const float4*)(fb + c*HW);
    float a2 = 0.f;
    #pragma unroll
    for (int k = 0; k < 16; ++k){
      float4 v4 = row[k];
      a2 = fmaf(v4.x, attv[k*4+0], a2);
      a2 = fmaf(v4.y, attv[k*4+1], a2);
      a2 = fmaf(v4.z, attv[k*4+2], a2);
      a2 = fmaf(v4.w, attv[k*4+3], a2);
    }
    att_feat[(size_t)b*FEAT + c] = __float2bfloat16(a2);
  }
}

// ---------------- bf16 MFMA GEMM (NT) for gi_base preamble ----------------
__global__ __launch_bounds__(256) void gemm_mfma(const bf16_t* __restrict__ A,
                                                 const bf16_t* __restrict__ W,
                                                 const float* __restrict__ bias,
                                                 float* __restrict__ C,
                                                 int K, int lda, int ldw, int ldc){
  const int tid = threadIdx.x;
  const int w = tid >> 6, lane = tid & 63;
  const int r = lane & 15, half = lane >> 4;
  const int m_base = blockIdx.y * 64;
  const int n_base = blockIdx.x * 64 + w * 16;
  const bf16_t* Ap = A + (size_t)(m_base + r)*lda + half*8;
  const bf16_t* Wp = W + (size_t)(n_base + r)*ldw + half*8;
  f32x4 acc[4] = {};
  for (int k0 = 0; k0 < K; k0 += 32){
    bf16x8 bfrag = *(const bf16x8*)(Wp + k0);
    #pragma unroll
    for (int i = 0; i < 4; ++i){
      bf16x8 afrag = *(const bf16x8*)(Ap + (size_t)i*16*lda + k0);
      acc[i] = MFMA(afrag, bfrag, acc[i]);
    }
  }
  const float bv = bias ? bias[n_base + r] : 0.f;
  #pragma unroll
  for (int i = 0; i < 4; ++i)
    #pragma unroll
    for (int q = 0; q < 4; ++q)
      C[(size_t)(m_base + i*16 + half*4 + q)*ldc + n_base + r] = acc[i][q] + bv;
}

// ---------------- per-bg barrier (32 blocks, monotone counter) ----------------
static __device__ __forceinline__ void bg_barrier(uint32_t* bar, uint32_t target){
  __syncthreads();
  if (threadIdx.x == 0){
    __threadfence();   // publish stores, agent scope
    __hip_atomic_fetch_add(bar, 1u, __ATOMIC_RELEASE, __HIP_MEMORY_SCOPE_AGENT);
    while (__hip_atomic_load(bar, __ATOMIC_ACQUIRE, __HIP_MEMORY_SCOPE_AGENT) < target)
      __builtin_amdgcn_s_sleep(2);
    __threadfence();
  }
  __syncthreads();
}

// ---------------- cooperative scan kernel ----------------
// 256 blocks = 8 bg x 32. Block owns 16 h-cols: Wc slice (48x576) LDS-resident,
// gi_base slice in registers. h double-buffered bf16 in global. 2 barriers/step.
__global__ __launch_bounds__(512, 2) void mega2_kernel(
    const float* __restrict__ gi_base,
    const bf16_t* __restrict__ w_perm,
    const bf16_t* __restrict__ w_ssn,
    const bf16_t* __restrict__ lin1_wb,
    const float* __restrict__ lin1_b,
    const bf16_t* __restrict__ lin2_wp,
    const float* __restrict__ lin2_b,
    const float* __restrict__ b_hh,
    const float* __restrict__ gt,
    const int* __restrict__ line_prob,
    const float* __restrict__ sample_prob,
    float* __restrict__ out,
    bf16_t* __restrict__ h0,
    bf16_t* __restrict__ h1,
    bf16_t* __restrict__ ssb,
    uint32_t* __restrict__ bars)
{
  __shared__ bf16_t wc[48][584];     // block's 48 gate rows, padded stride
  __shared__ bf16_t wssn[16][72];
  __shared__ bf16_t o1s[16][520];

  const int tid = threadIdx.x;
  const int wv = tid >> 6, lane = tid & 63;
  const int lr = lane & 15, half = lane >> 4;
  const int bid = blockIdx.x;
  const int bg = bid >> 5, lb = bid & 31;
  const int hc0 = lb * 16;
  const int bgrow = bg * BGR;
  uint32_t* bar = bars + bg * 64;

  // stage weight slices into LDS (once)
  for (int i = tid; i < 3456; i += 512){
    int row = i / 72, c = (i % 72) * 8;
    *(uint4*)&wc[row][c] = *(const uint4*)(w_perm + (size_t)(lb*48 + row)*KC + c);
  }
  for (int i = tid; i < 128; i += 512){
    int row = i >> 3, c = (i & 7) * 8;
    *(uint4*)&wssn[row][c] = *(const uint4*)(w_ssn + (size_t)(hc0 + row)*64 + c);
  }

  // per-thread constants / register-resident gi_base slice
  const int r0 = bgrow + wv*32;
  const int col = hc0 + lr;
  float gir[2][4], giz[2][4], gin_[2][4];
  #pragma unroll
  for (int mt = 0; mt < 2; ++mt)
    #pragma unroll
    for (int q = 0; q < 4; ++q){
      const float* gp = gi_base + (size_t)(r0 + mt*16 + half*4 + q)*G3 + col;
      gir[mt][q]  = gp[0];
      giz[mt][q]  = gp[512];
      gin_[mt][q] = gp[1024];
    }
  const float bhn = b_hh[1024 + col];
  float lb1[4];
  #pragma unroll
  for (int nt = 0; nt < 4; ++nt) lb1[nt] = lin1_b[wv*64 + nt*16 + lr];
  const int j3 = wv*16 + lr;
  float b2c = 0.f;
  if (wv < 3 && j3 < OUTSZ) b2c = lin2_b[j3];
  const int rb = bgrow + lb*16;

  float hp[2][4] = {};   // fp32 master h for this thread's 8 (row,col) cells
  uint32_t bt = 0;
  __syncthreads();

  for (int t = 0; t < NL; ++t){
    const bf16_t* hA = ((t & 1) == 0) ? h1 : h0;   // h(t-1)
    bf16_t*       hW = ((t & 1) == 0) ? h0 : h1;   // h(t)

    // ---- phase A: ghss = [h|ss] @ Wc^T (K=576) + ssn (K=64) ----
    f32x4 accA[2][3] = {};
    f32x4 accS[2] = {};
    #pragma unroll 4
    for (int k0 = 0; k0 < 16; ++k0){
      const int kc = k0*32 + half*8;
      bf16x8 a0 = *(const bf16x8*)(hA + (size_t)(r0 + lr)*512 + kc);
      bf16x8 a1 = *(const bf16x8*)(hA + (size_t)(r0 + 16 + lr)*512 + kc);
      bf16x8 b0 = *(const bf16x8*)&wc[lr][kc];
      bf16x8 b1 = *(const bf16x8*)&wc[16 + lr][kc];
      bf16x8 b2 = *(const bf16x8*)&wc[32 + lr][kc];
      accA[0][0] = MFMA(a0, b0, accA[0][0]);
      accA[0][1] = MFMA(a0, b1, accA[0][1]);
      accA[0][2] = MFMA(a0, b2, accA[0][2]);
      accA[1][0] = MFMA(a1, b0, accA[1][0]);
      accA[1][1] = MFMA(a1, b1, accA[1][1]);
      accA[1][2] = MFMA(a1, b2, accA[1][2]);
    }
    #pragma unroll
    for (int ks = 0; ks < 2; ++ks){
      const int kc = ks*32 + half*8;
      bf16x8 a0 = *(const bf16x8*)(ssb + (size_t)(r0 + lr)*64 + kc);
      bf16x8 a1 = *(const bf16x8*)(ssb + (size_t)(r0 + 16 + lr)*64 + kc);
      bf16x8 b0 = *(const bf16x8*)&wc[lr][512 + kc];
      bf16x8 b1 = *(const bf16x8*)&wc[16 + lr][512 + kc];
      bf16x8 bs = *(const bf16x8*)&wssn[lr][kc];
      accA[0][0] = MFMA(a0, b0, accA[0][0]);
      accA[0][1] = MFMA(a0, b1, accA[0][1]);
      accA[1][0] = MFMA(a1, b0, accA[1][0]);
      accA[1][1] = MFMA(a1, b1, accA[1][1]);
      // n-gate rows have zero ss-cols in wc; input-side n goes through wssn:
      accS[0] = MFMA(a0, bs, accS[0]);
      accS[1] = MFMA(a1, bs, accS[1]);
    }

    // ---- gates ----
    #pragma unroll
    for (int mt = 0; mt < 2; ++mt)
      #pragma unroll
      for (int q = 0; q < 4; ++q){
        float ir = accA[mt][0][q] + gir[mt][q];          // incl b_ih_r + b_hh_r
        float iz = accA[mt][1][q] + giz[mt][q];
        float hn = accA[mt][2][q] + bhn;
        float gn = gin_[mt][q] + accS[mt][q];
        float r = sigmoidf_(ir);
        float z = sigmoidf_(iz);
        float n = tanhf(gn + r*hn);
        float hv = (1.f - z)*n + z*hp[mt][q];
        hp[mt][q] = hv;
        int row = r0 + mt*16 + half*4 + q;
        hW[(size_t)row*512 + col] = __float2bfloat16(hv);
      }

    bt += 32; bg_barrier(bar, bt);   // h(t) published

    // ---- phase B+C: blocks lb<16 do 16 rows' MLP ----
    if (lb < 16){
      const bf16_t* hB = hW;
      f32x4 accB[4] = {};
      #pragma unroll 4
      for (int k0 = 0; k0 < 16; ++k0){
        const int kc = k0*32 + half*8;
        union { u16x8 u; bf16x8 b; } va;
        va.u = *(const u16x8*)(hB + (size_t)(rb + lr)*512 + kc);
        #pragma unroll
        for (int e = 0; e < 8; ++e) va.u[e] = (va.u[e] & 0x8000) ? (unsigned short)0 : va.u[e];
        #pragma unroll
        for (int nt = 0; nt < 4; ++nt){
          bf16x8 bf = *(const bf16x8*)(lin1_wb + (size_t)(wv*64 + nt*16 + lr)*512 + kc);
          accB[nt] = MFMA(va.b, bf, accB[nt]);
        }
      }
      #pragma unroll
      for (int nt = 0; nt < 4; ++nt)
        #pragma unroll
        for (int q = 0; q < 4; ++q)
          o1s[half*4 + q][wv*64 + nt*16 + lr] = __float2bfloat16(fmaxf(accB[nt][q] + lb1[nt], 0.f));
    }
    __syncthreads();   // o1s ready (block-local)
    if (lb < 16 && wv < 3){
      f32x4 accC = {};
      #pragma unroll 4
      for (int k0 = 0; k0 < 16; ++k0){
        const int kc = k0*32 + half*8;
        bf16x8 af = *(const bf16x8*)&o1s[lr][kc];
        bf16x8 bf = *(const bf16x8*)(lin2_wp + (size_t)j3*512 + kc);
        accC = MFMA(af, bf, accC);
      }
      #pragma unroll
      for (int q = 0; q < 4; ++q){
        float val = accC[q] + b2c;
        int bm = rb + half*4 + q;
        if (j3 < 40){
          out[((size_t)bm*NL + t)*40 + j3] = val;
        } else if (j3 < 42){
          float other = __shfl_xor(val, 1);
          float mx = fmaxf(val, other);
          float e0 = __expf(val - mx), e1 = __expf(other - mx);
          out[(size_t)B*NL*40 + ((size_t)bm*NL + t)*2 + (j3 - 40)] = e0/(e0 + e1);
        }
        if (t + 1 < NL && j3 < OUTSZ){
          bool up = sample_prob[(size_t)(t+1)*B + bm] < 0.1f;
          float gtv;
          if (j3 < 40) gtv = gt[((size_t)bm*NL + t)*40 + j3];
          else {
            float pv = (float)line_prob[bm*NL + t];
            gtv = (j3 == 40) ? 1.f - pv : pv;
          }
          ssb[(size_t)bm*64 + j3] = __float2bfloat16(up ? val : gtv);
        }
      }
    }

    bt += 32; bg_barrier(bar, bt);   // ss(t+1), out published
  }
}

extern "C" void kernel_launch(void* const* d_in, const int* in_sizes, int n_in,
                              void* d_out, int out_size, void* d_ws, size_t ws_size,
                              hipStream_t stream) {
  const float* img         = (const float*)d_in[0];
  const float* gt          = (const float*)d_in[1];
  const int*   line_prob   = (const int*)d_in[2];
  const float* sample_prob = (const float*)d_in[3];
  const float* att_w       = (const float*)d_in[4];
  // d_in[5] att_b: unused — softmax shift-invariance cancels it
  const float* w_ih        = (const float*)d_in[6];
  const float* w_hh        = (const float*)d_in[7];
  const float* b_ih        = (const float*)d_in[8];
  const float* b_hh        = (const float*)d_in[9];
  const float* lin1_w      = (const float*)d_in[10];
  const float* lin1_b      = (const float*)d_in[11];
  const float* lin2_w      = (const float*)d_in[12];
  const float* lin2_b      = (const float*)d_in[13];
  float* out = (float*)d_out;

  char* p = (char*)d_ws;
  auto alloc = [&](size_t bytes){ void* q = p; p += (bytes + 255) & ~(size_t)255; return q; };
  float*    gi_base   = (float*)alloc((size_t)B*G3*4);
  bf16_t*   att_bf    = (bf16_t*)alloc((size_t)B*FEAT*2);
  bf16_t*   w_perm    = (bf16_t*)alloc((size_t)G3*KC*2);
  bf16_t*   w_ssn     = (bf16_t*)alloc((size_t)512*64*2);
  bf16_t*   lin1_wb   = (bf16_t*)alloc((size_t)512*512*2);
  bf16_t*   lin2_wp   = (bf16_t*)alloc((size_t)48*512*2);
  bf16_t*   w_ih512b  = (bf16_t*)alloc((size_t)G3*512*2);
  float*    bias_comb = (float*)alloc((size_t)G3*4);
  bf16_t*   h0        = (bf16_t*)alloc((size_t)B*512*2);
  bf16_t*   h1        = (bf16_t*)alloc((size_t)B*512*2);
  bf16_t*   ssb       = (bf16_t*)alloc((size_t)B*64*2);
  uint32_t* bars      = (uint32_t*)alloc((size_t)NBG*64*4);

  // h1 (read at t=0), ss, barrier counters must start zeroed every call
  hipMemsetAsync(h0,   0, (size_t)B*512*2*2 + (size_t)B*64*2, stream);  // h0,h1,ssb contiguous
  hipMemsetAsync(bars, 0, (size_t)NBG*64*4, stream);

  prep2_kernel<<<4096, 256, 0, stream>>>(w_ih, w_hh, lin1_w, lin2_w, b_ih, b_hh,
                                         w_perm, w_ssn, lin1_wb, lin2_wp,
                                         w_ih512b, bias_comb);
  att_kernel<<<B, 256, 0, stream>>>(img, att_w, att_bf);
  gemm_mfma<<<dim3(G3/64, B/64), 256, 0, stream>>>(att_bf, w_ih512b, bias_comb, gi_base,
                                                   512, 512, 512, G3);

  void* args[] = {&gi_base, &w_perm, &w_ssn, &lin1_wb, (void*)&lin1_b,
                  &lin2_wp, (void*)&lin2_b, (void*)&b_hh, (void*)&gt,
                  (void*)&line_prob, (void*)&sample_prob, &out, &h0, &h1, &ssb, &bars};
  hipLaunchCooperativeKernel((const void*)mega2_kernel, dim3(NBG*NPB), dim3(512),
                             args, 0, stream);
}

// Round 7
// 2395.048 us; speedup vs baseline: 3.4812x; 3.4812x over previous
//
#include <hip/hip_runtime.h>
#include <hip/hip_bf16.h>
#include <cstdint>

#define B 2048
#define NL 32
#define FEAT 512
#define HID 512
#define HW 64
#define OUTSZ 42
#define G3 1536
#define LDIH 554   // gru_w_ih row stride
#define KC 576     // K for ghss GEMM: 512 h + 42 ss + 22 pad
#define MB 16      // batch rows per block
#define NBLK (B/MB)   // 128
#define LDX 584    // lds_x row stride (576 + 8); word-stride 292 % 32 == 4 -> balanced banks
#define LDH 520    // hrelu/o1 row stride (512 + 8); 260 % 32 == 4

typedef __bf16 bf16x8 __attribute__((ext_vector_type(8)));
typedef float f32x4 __attribute__((ext_vector_type(4)));
typedef __hip_bfloat16 bf16_t;

#define MFMA(a,b,c) __builtin_amdgcn_mfma_f32_16x16x32_bf16(a,b,c,0,0,0)

static __device__ __forceinline__ float sigmoidf_(float x){ return 1.f/(1.f+__expf(-x)); }

// ---------------- one-time weight prep ----------------
// w_comb [1536][576] (original row order): cols 0..511 = w_hh;
//   cols 512..553 = w_ih ss-cols for r/z gate rows (<1024) ONLY (zero for n rows); rest 0.
// w_ssn [512][64]: n-gate input-side ss weights (w_ih rows 1024+j, cols 512..553), padded.
// lin1_wb [512][512]; lin2_wp [48][512] (rows 42..47 zero); w_ih512b [1536][512];
// bias_comb [1536] = b_ih + (gate<2 ? b_hh : 0)   (n-gate's b_hh stays hidden-side).
__global__ __launch_bounds__(256) void prep2_kernel(
    const float* __restrict__ w_ih, const float* __restrict__ w_hh,
    const float* __restrict__ lin1_w, const float* __restrict__ lin2_w,
    const float* __restrict__ b_ih, const float* __restrict__ b_hh,
    bf16_t* __restrict__ w_comb, bf16_t* __restrict__ w_ssn,
    bf16_t* __restrict__ lin1_wb, bf16_t* __restrict__ lin2_wp,
    bf16_t* __restrict__ w_ih512b, float* __restrict__ bias_comb){
  const int NP = G3*KC, NS = 512*64, NL1 = 512*512, NL2 = 48*512, NI = G3*512, NB = G3;
  const int total = NP+NS+NL1+NL2+NI+NB;
  for (int idx = blockIdx.x*256 + threadIdx.x; idx < total; idx += gridDim.x*256){
    int i = idx;
    if (i < NP){
      int r = i / KC, k = i % KC;
      float v = (k < 512) ? w_hh[r*512 + k]
              : ((k < 512 + OUTSZ && r < 1024) ? w_ih[(size_t)r*LDIH + k] : 0.f);
      w_comb[i] = __float2bfloat16(v);
    } else if ((i -= NP) < NS){
      int j = i >> 6, k = i & 63;
      float v = (k < OUTSZ) ? w_ih[(size_t)(1024+j)*LDIH + 512 + k] : 0.f;
      w_ssn[i] = __float2bfloat16(v);
    } else if ((i -= NS) < NL1){
      lin1_wb[i] = __float2bfloat16(lin1_w[i]);
    } else if ((i -= NL1) < NL2){
      int j = i >> 9, k = i & 511;
      lin2_wp[i] = __float2bfloat16(j < OUTSZ ? lin2_w[j*512 + k] : 0.f);
    } else if ((i -= NL2) < NI){
      int r = i >> 9, c = i & 511;
      w_ih512b[i] = __float2bfloat16(w_ih[(size_t)r*LDIH + c]);
    } else {
      int j = i - NI;
      bias_comb[j] = b_ih[j] + (j < 1024 ? b_hh[j] : 0.f);
    }
  }
}

// ---------------- attention precompute (step-invariant) ----------------
__global__ __launch_bounds__(256) void att_kernel(const float* __restrict__ feat,
                                                  const float* __restrict__ att_w,
                                                  bf16_t* __restrict__ att_feat){
  int b = blockIdx.x;
  const float* fb = feat + (size_t)b * FEAT * HW;
  __shared__ float part[4][64];
  __shared__ float attv[64];
  int t = threadIdx.x;
  int s = t & 63, q = t >> 6;
  float acc = 0.f;
  for (int c = q*128; c < q*128 + 128; ++c)
    acc = fmaf(fb[c*HW + s], att_w[c], acc);
  part[q][s] = acc;
  __syncthreads();
  if (t < 64){
    float v = part[0][t] + part[1][t] + part[2][t] + part[3][t];
    float m = v;
    for (int o = 32; o > 0; o >>= 1) m = fmaxf(m, __shfl_xor(m, o));
    float e = __expf(v - m);
    float ssum = e;
    for (int o = 32; o > 0; o >>= 1) ssum += __shfl_xor(ssum, o);
    attv[t] = e / ssum * 2.0f;   // * BETA
  }
  __syncthreads();
  for (int c = t; c < FEAT; c += 256){
    const float4* row = (const float4*)(fb + c*HW);
    float a2 = 0.f;
    #pragma unroll
    for (int k = 0; k < 16; ++k){
      float4 v4 = row[k];
      a2 = fmaf(v4.x, attv[k*4+0], a2);
      a2 = fmaf(v4.y, attv[k*4+1], a2);
      a2 = fmaf(v4.z, attv[k*4+2], a2);
      a2 = fmaf(v4.w, attv[k*4+3], a2);
    }
    att_feat[(size_t)b*FEAT + c] = __float2bfloat16(a2);
  }
}

// ---------------- bf16 MFMA GEMM (NT) for gi_base preamble ----------------
__global__ __launch_bounds__(256) void gemm_mfma(const bf16_t* __restrict__ A,
                                                 const bf16_t* __restrict__ W,
                                                 const float* __restrict__ bias,
                                                 float* __restrict__ C,
                                                 int K, int lda, int ldw, int ldc){
  const int tid = threadIdx.x;
  const int w = tid >> 6, lane = tid & 63;
  const int r = lane & 15, half = lane >> 4;
  const int m_base = blockIdx.y * 64;
  const int n_base = blockIdx.x * 64 + w * 16;
  const bf16_t* Ap = A + (size_t)(m_base + r)*lda + half*8;
  const bf16_t* Wp = W + (size_t)(n_base + r)*ldw + half*8;
  f32x4 acc[4] = {};
  for (int k0 = 0; k0 < K; k0 += 32){
    bf16x8 bfrag = *(const bf16x8*)(Wp + k0);
    #pragma unroll
    for (int i = 0; i < 4; ++i){
      bf16x8 afrag = *(const bf16x8*)(Ap + (size_t)i*16*lda + k0);
      acc[i] = MFMA(afrag, bfrag, acc[i]);
    }
  }
  const float bv = bias ? bias[n_base + r] : 0.f;
  #pragma unroll
  for (int i = 0; i < 4; ++i)
    #pragma unroll
    for (int q = 0; q < 4; ++q)
      C[(size_t)(m_base + i*16 + half*4 + q)*ldc + n_base + r] = acc[i][q] + bv;
}

// ---------------- the whole 32-step scan: one block owns 16 batch rows ----------------
// 1024 threads = 16 waves. Wave wv owns h-columns [wv*32, wv*32+32) (ti in {0,1})
// for the single 16-row m-tile. Coverage: 16 waves x 32 cols = 512 cols, 16 rows. Full.
// gi_base slice register-resident: 24 f32/thread, loaded ONCE (step-invariant).
__global__ __launch_bounds__(1024) void mega4_kernel(
    const float* __restrict__ gi_base,     // [B][1536] incl b_ih (+b_hh for r/z)
    const bf16_t* __restrict__ w_comb,     // [1536][576]
    const bf16_t* __restrict__ w_ssn,      // [512][64]
    const bf16_t* __restrict__ lin1_wb,    // [512][512]
    const float* __restrict__ lin1_b,
    const bf16_t* __restrict__ lin2_wp,    // [48][512]
    const float* __restrict__ lin2_b,
    const float* __restrict__ b_hh,
    const float* __restrict__ gt,
    const int* __restrict__ line_prob,
    const float* __restrict__ sample_prob,
    float* __restrict__ out){
  __shared__ bf16_t lds_x[MB][LDX];    // [h(512) | ss(42) | zero-pad(22) | pad]
  __shared__ bf16_t hrelu[MB][LDH];
  __shared__ bf16_t o1s[MB][LDH];
  const int tid = threadIdx.x;
  const int wv = tid >> 6, l = tid & 63;
  const int lr = l & 15, half = l >> 4;      // half in 0..3 (k-quarter / D-row group)
  const int m0 = blockIdx.x * MB;
  const int colbase = wv * 32;

  // zero lds_x (h=0, ss=0 at t=0; pad cols stay 0 forever)
  for (int i = tid; i < MB*LDX/2; i += 1024) ((uint32_t*)lds_x)[i] = 0u;

  // ---- register-resident gi_base slice: 2(ti) x 4(q) x 3 gates = 24 f32 ----
  float gir[2][4], giz[2][4], gin_[2][4];
  #pragma unroll
  for (int ti = 0; ti < 2; ++ti)
    #pragma unroll
    for (int q = 0; q < 4; ++q){
      const float* gp = gi_base + (size_t)(m0 + half*4 + q)*G3 + colbase + ti*16 + lr;
      gir[ti][q]  = gp[0];
      giz[ti][q]  = gp[512];
      gin_[ti][q] = gp[1024];
    }
  float bhn[2], lb1[2];
  #pragma unroll
  for (int ti = 0; ti < 2; ++ti){
    bhn[ti] = b_hh[1024 + colbase + ti*16 + lr];
    lb1[ti] = lin1_b[colbase + ti*16 + lr];
  }
  const int j3 = wv*16 + lr;                 // phase-C output column (waves 0..2)
  const float b2c = (wv < 3 && j3 < OUTSZ) ? lin2_b[j3] : 0.f;

  // weight base pointers (B-fragment rows = 16 contiguous original rows)
  const bf16_t* wcp = w_comb  + (size_t)(colbase + lr)*KC + half*8;
  const bf16_t* wsp = w_ssn   + (size_t)(colbase + lr)*64 + half*8;
  const bf16_t* l1p = lin1_wb + (size_t)(colbase + lr)*512 + half*8;
  const bf16_t* l2p = lin2_wp + (size_t)(wv < 3 ? j3 : 0)*512 + half*8;

  float hp[2][4] = {};                 // fp32 master h for this thread's 8 cells
  __syncthreads();

  for (int t = 0; t < NL; ++t){
    // ---- phase A: ghss = [h|ss] @ w_comb^T (K=576) + input-side n-ss (K=64) ----
    f32x4 accA[3][2] = {};             // [gate][ti]
    f32x4 accS[2] = {};
    #pragma unroll 3
    for (int k0 = 0; k0 < 18; ++k0){
      bf16x8 a = *(const bf16x8*)&lds_x[lr][k0*32 + half*8];
      #pragma unroll
      for (int g = 0; g < 3; ++g)
        #pragma unroll
        for (int ti = 0; ti < 2; ++ti){
          bf16x8 bf = *(const bf16x8*)(wcp + (size_t)(g*512 + ti*16)*KC + k0*32);
          accA[g][ti] = MFMA(a, bf, accA[g][ti]);
        }
    }
    #pragma unroll
    for (int ks = 0; ks < 2; ++ks){
      bf16x8 a = *(const bf16x8*)&lds_x[lr][512 + ks*32 + half*8];
      #pragma unroll
      for (int ti = 0; ti < 2; ++ti){
        bf16x8 bs = *(const bf16x8*)(wsp + (size_t)(ti*16)*64 + ks*32);
        accS[ti] = MFMA(a, bs, accS[ti]);
      }
    }
    __syncthreads();   // all lds_x reads done before gates rewrite h-cols

    // ---- gates ----
    #pragma unroll
    for (int ti = 0; ti < 2; ++ti)
      #pragma unroll
      for (int q = 0; q < 4; ++q){
        float ir = accA[0][ti][q] + gir[ti][q];     // incl b_ih_r + b_hh_r
        float iz = accA[1][ti][q] + giz[ti][q];
        float hn = accA[2][ti][q] + bhn[ti];
        float gn = gin_[ti][q] + accS[ti][q];
        float r = sigmoidf_(ir);
        float z = sigmoidf_(iz);
        float n = tanhf(gn + r*hn);
        float hv = (1.f - z)*n + z*hp[ti][q];
        hp[ti][q] = hv;
        int row = half*4 + q;
        int col = colbase + ti*16 + lr;
        lds_x[row][col] = __float2bfloat16(hv);
        hrelu[row][col] = __float2bfloat16(fmaxf(hv, 0.f));
      }
    __syncthreads();   // h, hrelu ready

    // ---- phase B: o1 = relu(hrelu @ lin1^T + b1) (K=512) ----
    {
      f32x4 accB[2] = {};
      #pragma unroll 4
      for (int k0 = 0; k0 < 16; ++k0){
        bf16x8 a = *(const bf16x8*)&hrelu[lr][k0*32 + half*8];
        #pragma unroll
        for (int ti = 0; ti < 2; ++ti){
          bf16x8 bf = *(const bf16x8*)(l1p + (size_t)(ti*16)*512 + k0*32);
          accB[ti] = MFMA(a, bf, accB[ti]);
        }
      }
      #pragma unroll
      for (int ti = 0; ti < 2; ++ti)
        #pragma unroll
        for (int q = 0; q < 4; ++q)
          o1s[half*4 + q][colbase + ti*16 + lr] =
              __float2bfloat16(fmaxf(accB[ti][q] + lb1[ti], 0.f));
    }
    __syncthreads();   // o1s ready

    // ---- phase C (waves 0..2): lin2 + outputs + ss_{t+1} ----
    if (wv < 3){
      f32x4 accC = {};
      #pragma unroll 4
      for (int k0 = 0; k0 < 16; ++k0){
        bf16x8 a = *(const bf16x8*)&o1s[lr][k0*32 + half*8];
        bf16x8 bf = *(const bf16x8*)(l2p + k0*32);
        accC = MFMA(a, bf, accC);
      }
      #pragma unroll
      for (int q = 0; q < 4; ++q){
        float val = accC[q] + b2c;
        int row = half*4 + q;
        int bm = m0 + row;
        if (j3 < 40){
          out[((size_t)bm*NL + t)*40 + j3] = val;
        } else if (j3 < 42){
          float other = __shfl_xor(val, 1);
          float mx = fmaxf(val, other);
          float e0 = __expf(val - mx), e1 = __expf(other - mx);
          out[(size_t)B*NL*40 + ((size_t)bm*NL + t)*2 + (j3 - 40)] = e0/(e0 + e1);
        }
        if (t + 1 < NL && j3 < OUTSZ){
          bool up = sample_prob[(size_t)(t+1)*B + bm] < 0.1f;
          float gtv;
          if (j3 < 40) gtv = gt[((size_t)bm*NL + t)*40 + j3];
          else {
            float pv = (float)line_prob[bm*NL + t];
            gtv = (j3 == 40) ? 1.f - pv : pv;
          }
          lds_x[row][512 + j3] = __float2bfloat16(up ? val : gtv);
        }
      }
    }
    __syncthreads();   // ss ready for next step's phase A
  }
}

extern "C" void kernel_launch(void* const* d_in, const int* in_sizes, int n_in,
                              void* d_out, int out_size, void* d_ws, size_t ws_size,
                              hipStream_t stream) {
  const float* img         = (const float*)d_in[0];
  const float* gt          = (const float*)d_in[1];
  const int*   line_prob   = (const int*)d_in[2];
  const float* sample_prob = (const float*)d_in[3];
  const float* att_w       = (const float*)d_in[4];
  // d_in[5] att_b: unused — softmax shift-invariance cancels it
  const float* w_ih        = (const float*)d_in[6];
  const float* w_hh        = (const float*)d_in[7];
  const float* b_ih        = (const float*)d_in[8];
  const float* b_hh        = (const float*)d_in[9];
  const float* lin1_w      = (const float*)d_in[10];
  const float* lin1_b      = (const float*)d_in[11];
  const float* lin2_w      = (const float*)d_in[12];
  const float* lin2_b      = (const float*)d_in[13];
  float* out = (float*)d_out;

  char* p = (char*)d_ws;
  auto alloc = [&](size_t bytes){ void* q = p; p += (bytes + 255) & ~(size_t)255; return q; };
  float*  gi_base   = (float*)alloc((size_t)B*G3*4);
  bf16_t* att_bf    = (bf16_t*)alloc((size_t)B*FEAT*2);
  bf16_t* w_comb    = (bf16_t*)alloc((size_t)G3*KC*2);
  bf16_t* w_ssn     = (bf16_t*)alloc((size_t)512*64*2);
  bf16_t* lin1_wb   = (bf16_t*)alloc((size_t)512*512*2);
  bf16_t* lin2_wp   = (bf16_t*)alloc((size_t)48*512*2);
  bf16_t* w_ih512b  = (bf16_t*)alloc((size_t)G3*512*2);
  float*  bias_comb = (float*)alloc((size_t)G3*4);

  prep2_kernel<<<4096, 256, 0, stream>>>(w_ih, w_hh, lin1_w, lin2_w, b_ih, b_hh,
                                         w_comb, w_ssn, lin1_wb, lin2_wp,
                                         w_ih512b, bias_comb);
  att_kernel<<<B, 256, 0, stream>>>(img, att_w, att_bf);
  // gi_base = att_feat @ W_ih[:, :512]^T + b_ih + (b_hh for r/z)   (step-invariant)
  gemm_mfma<<<dim3(G3/64, B/64), 256, 0, stream>>>(att_bf, w_ih512b, bias_comb, gi_base,
                                                   512, 512, 512, G3);
  mega4_kernel<<<NBLK, 1024, 0, stream>>>(gi_base, w_comb, w_ssn, lin1_wb, lin1_b,
                                          lin2_wp, lin2_b, b_hh,
                                          gt, line_prob, sample_prob, out);
}

// Round 8
// 2338.076 us; speedup vs baseline: 3.5660x; 1.0244x over previous
//
#include <hip/hip_runtime.h>
#include <hip/hip_bf16.h>
#include <cstdint>

#define B 2048
#define NL 32
#define FEAT 512
#define HID 512
#define HW 64
#define OUTSZ 42
#define G3 1536
#define LDIH 554   // gru_w_ih row stride
#define KC 576     // K for ghss GEMM: 512 h + 42 ss + 22 pad
#define MB 16      // batch rows per block
#define NBLK (B/MB)   // 128
#define LDX 584    // lds_x row stride (576 + 8); word-stride 292 % 32 == 4 -> balanced banks
#define LDH 520    // hrelu/o1 row stride (512 + 8); 260 % 32 == 4

typedef __bf16 bf16x8 __attribute__((ext_vector_type(8)));
typedef float f32x4 __attribute__((ext_vector_type(4)));
typedef __hip_bfloat16 bf16_t;

#define MFMA(a,b,c) __builtin_amdgcn_mfma_f32_16x16x32_bf16(a,b,c,0,0,0)

static __device__ __forceinline__ float sigmoidf_(float x){ return 1.f/(1.f+__expf(-x)); }

// ---------------- one-time weight prep ----------------
// w_comb [1536][576] (original row order): cols 0..511 = w_hh;
//   cols 512..553 = w_ih ss-cols for r/z gate rows (<1024) ONLY (zero for n rows); rest 0.
// w_ssn [512][64]: n-gate input-side ss weights (w_ih rows 1024+j, cols 512..553), padded.
// lin1_wb [512][512]; lin2_wp [48][512] (rows 42..47 zero); w_ih512b [1536][512];
// bias_comb [1536] = b_ih + (gate<2 ? b_hh : 0)   (n-gate's b_hh stays hidden-side).
__global__ __launch_bounds__(256) void prep2_kernel(
    const float* __restrict__ w_ih, const float* __restrict__ w_hh,
    const float* __restrict__ lin1_w, const float* __restrict__ lin2_w,
    const float* __restrict__ b_ih, const float* __restrict__ b_hh,
    bf16_t* __restrict__ w_comb, bf16_t* __restrict__ w_ssn,
    bf16_t* __restrict__ lin1_wb, bf16_t* __restrict__ lin2_wp,
    bf16_t* __restrict__ w_ih512b, float* __restrict__ bias_comb){
  const int NP = G3*KC, NS = 512*64, NL1 = 512*512, NL2 = 48*512, NI = G3*512, NB = G3;
  const int total = NP+NS+NL1+NL2+NI+NB;
  for (int idx = blockIdx.x*256 + threadIdx.x; idx < total; idx += gridDim.x*256){
    int i = idx;
    if (i < NP){
      int r = i / KC, k = i % KC;
      float v = (k < 512) ? w_hh[r*512 + k]
              : ((k < 512 + OUTSZ && r < 1024) ? w_ih[(size_t)r*LDIH + k] : 0.f);
      w_comb[i] = __float2bfloat16(v);
    } else if ((i -= NP) < NS){
      int j = i >> 6, k = i & 63;
      float v = (k < OUTSZ) ? w_ih[(size_t)(1024+j)*LDIH + 512 + k] : 0.f;
      w_ssn[i] = __float2bfloat16(v);
    } else if ((i -= NS) < NL1){
      lin1_wb[i] = __float2bfloat16(lin1_w[i]);
    } else if ((i -= NL1) < NL2){
      int j = i >> 9, k = i & 511;
      lin2_wp[i] = __float2bfloat16(j < OUTSZ ? lin2_w[j*512 + k] : 0.f);
    } else if ((i -= NL2) < NI){
      int r = i >> 9, c = i & 511;
      w_ih512b[i] = __float2bfloat16(w_ih[(size_t)r*LDIH + c]);
    } else {
      int j = i - NI;
      bias_comb[j] = b_ih[j] + (j < 1024 ? b_hh[j] : 0.f);
    }
  }
}

// ---------------- attention precompute (step-invariant) ----------------
__global__ __launch_bounds__(256) void att_kernel(const float* __restrict__ feat,
                                                  const float* __restrict__ att_w,
                                                  bf16_t* __restrict__ att_feat){
  int b = blockIdx.x;
  const float* fb = feat + (size_t)b * FEAT * HW;
  __shared__ float part[4][64];
  __shared__ float attv[64];
  int t = threadIdx.x;
  int s = t & 63, q = t >> 6;
  float acc = 0.f;
  for (int c = q*128; c < q*128 + 128; ++c)
    acc = fmaf(fb[c*HW + s], att_w[c], acc);
  part[q][s] = acc;
  __syncthreads();
  if (t < 64){
    float v = part[0][t] + part[1][t] + part[2][t] + part[3][t];
    float m = v;
    for (int o = 32; o > 0; o >>= 1) m = fmaxf(m, __shfl_xor(m, o));
    float e = __expf(v - m);
    float ssum = e;
    for (int o = 32; o > 0; o >>= 1) ssum += __shfl_xor(ssum, o);
    attv[t] = e / ssum * 2.0f;   // * BETA
  }
  __syncthreads();
  for (int c = t; c < FEAT; c += 256){
    const float4* row = (const float4*)(fb + c*HW);
    float a2 = 0.f;
    #pragma unroll
    for (int k = 0; k < 16; ++k){
      float4 v4 = row[k];
      a2 = fmaf(v4.x, attv[k*4+0], a2);
      a2 = fmaf(v4.y, attv[k*4+1], a2);
      a2 = fmaf(v4.z, attv[k*4+2], a2);
      a2 = fmaf(v4.w, attv[k*4+3], a2);
    }
    att_feat[(size_t)b*FEAT + c] = __float2bfloat16(a2);
  }
}

// ---------------- bf16 MFMA GEMM (NT) for gi_base preamble ----------------
__global__ __launch_bounds__(256) void gemm_mfma(const bf16_t* __restrict__ A,
                                                 const bf16_t* __restrict__ W,
                                                 const float* __restrict__ bias,
                                                 float* __restrict__ C,
                                                 int K, int lda, int ldw, int ldc){
  const int tid = threadIdx.x;
  const int w = tid >> 6, lane = tid & 63;
  const int r = lane & 15, half = lane >> 4;
  const int m_base = blockIdx.y * 64;
  const int n_base = blockIdx.x * 64 + w * 16;
  const bf16_t* Ap = A + (size_t)(m_base + r)*lda + half*8;
  const bf16_t* Wp = W + (size_t)(n_base + r)*ldw + half*8;
  f32x4 acc[4] = {};
  for (int k0 = 0; k0 < K; k0 += 32){
    bf16x8 bfrag = *(const bf16x8*)(Wp + k0);
    #pragma unroll
    for (int i = 0; i < 4; ++i){
      bf16x8 afrag = *(const bf16x8*)(Ap + (size_t)i*16*lda + k0);
      acc[i] = MFMA(afrag, bfrag, acc[i]);
    }
  }
  const float bv = bias ? bias[n_base + r] : 0.f;
  #pragma unroll
  for (int i = 0; i < 4; ++i)
    #pragma unroll
    for (int q = 0; q < 4; ++q)
      C[(size_t)(m_base + i*16 + half*4 + q)*ldc + n_base + r] = acc[i][q] + bv;
}

// ---------------- the whole 32-step scan: one block owns 16 batch rows ----------------
// 512 threads = 8 waves. Wave wv owns h-columns [wv*64, wv*64+64) (ti in 0..3)
// for the single 16-row m-tile. Coverage: 8 waves x 64 cols = 512 cols, 16 rows. Full.
// __launch_bounds__(512,2) -> 256-VGPR budget: gi slice (48 f32) register-resident,
// plus room for ~12-24 in-flight weight loads (the round-7 kernel had VGPR=64 and
// serialized every load against L2 latency).
__global__ __launch_bounds__(512, 2) void mega5_kernel(
    const float* __restrict__ gi_base,     // [B][1536] incl b_ih (+b_hh for r/z)
    const bf16_t* __restrict__ w_comb,     // [1536][576]
    const bf16_t* __restrict__ w_ssn,      // [512][64]
    const bf16_t* __restrict__ lin1_wb,    // [512][512]
    const float* __restrict__ lin1_b,
    const bf16_t* __restrict__ lin2_wp,    // [48][512]
    const float* __restrict__ lin2_b,
    const float* __restrict__ b_hh,
    const float* __restrict__ gt,
    const int* __restrict__ line_prob,
    const float* __restrict__ sample_prob,
    float* __restrict__ out){
  __shared__ bf16_t lds_x[MB][LDX];    // [h(512) | ss(42) | zero-pad(22) | pad]
  __shared__ bf16_t hrelu[MB][LDH];
  __shared__ bf16_t o1s[MB][LDH];
  const int tid = threadIdx.x;
  const int wv = tid >> 6, l = tid & 63;
  const int lr = l & 15, half = l >> 4;      // half in 0..3 (k-quarter / D-row group)
  const int m0 = blockIdx.x * MB;
  const int colbase = wv * 64;

  // zero lds_x (h=0, ss=0 at t=0; pad cols stay 0 forever)
  for (int i = tid; i < MB*LDX/2; i += 512) ((uint32_t*)lds_x)[i] = 0u;

  // ---- register-resident gi_base slice: 4(ti) x 4(q) x 3 gates = 48 f32 ----
  float gir[4][4], giz[4][4], gin_[4][4];
  #pragma unroll
  for (int ti = 0; ti < 4; ++ti)
    #pragma unroll
    for (int q = 0; q < 4; ++q){
      const float* gp = gi_base + (size_t)(m0 + half*4 + q)*G3 + colbase + ti*16 + lr;
      gir[ti][q]  = gp[0];
      giz[ti][q]  = gp[512];
      gin_[ti][q] = gp[1024];
    }
  float bhn[4], lb1[4];
  #pragma unroll
  for (int ti = 0; ti < 4; ++ti){
    bhn[ti] = b_hh[1024 + colbase + ti*16 + lr];
    lb1[ti] = lin1_b[colbase + ti*16 + lr];
  }
  const int j3 = wv*16 + lr;                 // phase-C output column (waves 0..2)
  const float b2c = (wv < 3 && j3 < OUTSZ) ? lin2_b[j3] : 0.f;

  // weight base pointers (B-fragment rows = 16 contiguous original rows per ti)
  const bf16_t* wcp = w_comb  + (size_t)(colbase + lr)*KC + half*8;
  const bf16_t* wsp = w_ssn   + (size_t)(colbase + lr)*64 + half*8;
  const bf16_t* l1p = lin1_wb + (size_t)(colbase + lr)*512 + half*8;
  const bf16_t* l2p = lin2_wp + (size_t)(wv < 3 ? j3 : 0)*512 + half*8;

  float hp[4][4] = {};                 // fp32 master h for this thread's 16 cells
  __syncthreads();

  for (int t = 0; t < NL; ++t){
    // ---- phase A: ghss = [h|ss] @ w_comb^T (K=576) + input-side n-ss (K=64) ----
    f32x4 accA[3][4] = {};             // [gate][ti]
    f32x4 accS[4] = {};
    #pragma unroll 3
    for (int k0 = 0; k0 < 18; ++k0){
      bf16x8 a = *(const bf16x8*)&lds_x[lr][k0*32 + half*8];
      #pragma unroll
      for (int g = 0; g < 3; ++g)
        #pragma unroll
        for (int ti = 0; ti < 4; ++ti){
          bf16x8 bf = *(const bf16x8*)(wcp + (size_t)(g*512 + ti*16)*KC + k0*32);
          accA[g][ti] = MFMA(a, bf, accA[g][ti]);
        }
    }
    #pragma unroll
    for (int ks = 0; ks < 2; ++ks){
      bf16x8 a = *(const bf16x8*)&lds_x[lr][512 + ks*32 + half*8];
      #pragma unroll
      for (int ti = 0; ti < 4; ++ti){
        bf16x8 bs = *(const bf16x8*)(wsp + (size_t)(ti*16)*64 + ks*32);
        accS[ti] = MFMA(a, bs, accS[ti]);
      }
    }
    __syncthreads();   // all lds_x reads done before gates rewrite h-cols

    // ---- gates ----
    #pragma unroll
    for (int ti = 0; ti < 4; ++ti)
      #pragma unroll
      for (int q = 0; q < 4; ++q){
        float ir = accA[0][ti][q] + gir[ti][q];     // incl b_ih_r + b_hh_r
        float iz = accA[1][ti][q] + giz[ti][q];
        float hn = accA[2][ti][q] + bhn[ti];
        float gn = gin_[ti][q] + accS[ti][q];
        float r = sigmoidf_(ir);
        float z = sigmoidf_(iz);
        float n = tanhf(gn + r*hn);
        float hv = (1.f - z)*n + z*hp[ti][q];
        hp[ti][q] = hv;
        int row = half*4 + q;
        int col = colbase + ti*16 + lr;
        lds_x[row][col] = __float2bfloat16(hv);
        hrelu[row][col] = __float2bfloat16(fmaxf(hv, 0.f));
      }
    __syncthreads();   // h, hrelu ready

    // ---- phase B: o1 = relu(hrelu @ lin1^T + b1) (K=512) ----
    {
      f32x4 accB[4] = {};
      #pragma unroll 4
      for (int k0 = 0; k0 < 16; ++k0){
        bf16x8 a = *(const bf16x8*)&hrelu[lr][k0*32 + half*8];
        #pragma unroll
        for (int ti = 0; ti < 4; ++ti){
          bf16x8 bf = *(const bf16x8*)(l1p + (size_t)(ti*16)*512 + k0*32);
          accB[ti] = MFMA(a, bf, accB[ti]);
        }
      }
      #pragma unroll
      for (int ti = 0; ti < 4; ++ti)
        #pragma unroll
        for (int q = 0; q < 4; ++q)
          o1s[half*4 + q][colbase + ti*16 + lr] =
              __float2bfloat16(fmaxf(accB[ti][q] + lb1[ti], 0.f));
    }
    __syncthreads();   // o1s ready

    // ---- phase C (waves 0..2): lin2 + outputs + ss_{t+1} ----
    if (wv < 3){
      f32x4 accC = {};
      #pragma unroll 4
      for (int k0 = 0; k0 < 16; ++k0){
        bf16x8 a = *(const bf16x8*)&o1s[lr][k0*32 + half*8];
        bf16x8 bf = *(const bf16x8*)(l2p + k0*32);
        accC = MFMA(a, bf, accC);
      }
      #pragma unroll
      for (int q = 0; q < 4; ++q){
        float val = accC[q] + b2c;
        int row = half*4 + q;
        int bm = m0 + row;
        if (j3 < 40){
          out[((size_t)bm*NL + t)*40 + j3] = val;
        } else if (j3 < 42){
          float other = __shfl_xor(val, 1);
          float mx = fmaxf(val, other);
          float e0 = __expf(val - mx), e1 = __expf(other - mx);
          out[(size_t)B*NL*40 + ((size_t)bm*NL + t)*2 + (j3 - 40)] = e0/(e0 + e1);
        }
        if (t + 1 < NL && j3 < OUTSZ){
          bool up = sample_prob[(size_t)(t+1)*B + bm] < 0.1f;
          float gtv;
          if (j3 < 40) gtv = gt[((size_t)bm*NL + t)*40 + j3];
          else {
            float pv = (float)line_prob[bm*NL + t];
            gtv = (j3 == 40) ? 1.f - pv : pv;
          }
          lds_x[row][512 + j3] = __float2bfloat16(up ? val : gtv);
        }
      }
    }
    __syncthreads();   // ss ready for next step's phase A
  }
}

extern "C" void kernel_launch(void* const* d_in, const int* in_sizes, int n_in,
                              void* d_out, int out_size, void* d_ws, size_t ws_size,
                              hipStream_t stream) {
  const float* img         = (const float*)d_in[0];
  const float* gt          = (const float*)d_in[1];
  const int*   line_prob   = (const int*)d_in[2];
  const float* sample_prob = (const float*)d_in[3];
  const float* att_w       = (const float*)d_in[4];
  // d_in[5] att_b: unused — softmax shift-invariance cancels it
  const float* w_ih        = (const float*)d_in[6];
  const float* w_hh        = (const float*)d_in[7];
  const float* b_ih        = (const float*)d_in[8];
  const float* b_hh        = (const float*)d_in[9];
  const float* lin1_w      = (const float*)d_in[10];
  const float* lin1_b      = (const float*)d_in[11];
  const float* lin2_w      = (const float*)d_in[12];
  const float* lin2_b      = (const float*)d_in[13];
  float* out = (float*)d_out;

  char* p = (char*)d_ws;
  auto alloc = [&](size_t bytes){ void* q = p; p += (bytes + 255) & ~(size_t)255; return q; };
  float*  gi_base   = (float*)alloc((size_t)B*G3*4);
  bf16_t* att_bf    = (bf16_t*)alloc((size_t)B*FEAT*2);
  bf16_t* w_comb    = (bf16_t*)alloc((size_t)G3*KC*2);
  bf16_t* w_ssn     = (bf16_t*)alloc((size_t)512*64*2);
  bf16_t* lin1_wb   = (bf16_t*)alloc((size_t)512*512*2);
  bf16_t* lin2_wp   = (bf16_t*)alloc((size_t)48*512*2);
  bf16_t* w_ih512b  = (bf16_t*)alloc((size_t)G3*512*2);
  float*  bias_comb = (float*)alloc((size_t)G3*4);

  prep2_kernel<<<4096, 256, 0, stream>>>(w_ih, w_hh, lin1_w, lin2_w, b_ih, b_hh,
                                         w_comb, w_ssn, lin1_wb, lin2_wp,
                                         w_ih512b, bias_comb);
  att_kernel<<<B, 256, 0, stream>>>(img, att_w, att_bf);
  // gi_base = att_feat @ W_ih[:, :512]^T + b_ih + (b_hh for r/z)   (step-invariant)
  gemm_mfma<<<dim3(G3/64, B/64), 256, 0, stream>>>(att_bf, w_ih512b, bias_comb, gi_base,
                                                   512, 512, 512, G3);
  mega5_kernel<<<NBLK, 512, 0, stream>>>(gi_base, w_comb, w_ssn, lin1_wb, lin1_b,
                                         lin2_wp, lin2_b, b_hh,
                                         gt, line_prob, sample_prob, out);
}

// Round 9
// 1851.358 us; speedup vs baseline: 4.5035x; 1.2629x over previous
//
#include <hip/hip_runtime.h>
#include <hip/hip_bf16.h>
#include <cstdint>

#define B 2048
#define NL 32
#define FEAT 512
#define HID 512
#define HW 64
#define OUTSZ 42
#define G3 1536
#define LDIH 554   // gru_w_ih row stride
#define MB 16      // batch rows per block
#define NBLK (B/MB)   // 128
#define LDX 584    // lds_x row stride (576+8): word-stride % 32 == 4 -> 2-way (free)
#define LDH 520    // o1s row stride

typedef __bf16 bf16x8 __attribute__((ext_vector_type(8)));
typedef unsigned short u16x8 __attribute__((ext_vector_type(8)));
typedef float f32x4 __attribute__((ext_vector_type(4)));
typedef __hip_bfloat16 bf16_t;

#define MFMA(a,b,c) __builtin_amdgcn_mfma_f32_16x16x32_bf16(a,b,c,0,0,0)
#define WAITV(n) asm volatile("s_waitcnt vmcnt(" #n ")" ::: "memory")

static __device__ __forceinline__ float sigmoidf_(float x){ return 1.f/(1.f+__expf(-x)); }

static __device__ __forceinline__ void gld16(const bf16_t* g, bf16_t* l){
  __builtin_amdgcn_global_load_lds(
      (const __attribute__((address_space(1))) void*)g,
      (__attribute__((address_space(3))) void*)l, 16, 0, 0);
}

// ---------------- one-time weight prep into STAGING layouts ----------------
// sA[36][768][32]: chunk c=(k0,tig): row rp -> wv=rp/96, g=(rp%96)/32, l2, lr;
//   orig gate row = g*512 + wv*64 + (tig*2+l2)*16 + lr; 16B granule gq holds
//   k-quarter half = gq ^ (lr&3)  (XOR so staged-linear LDS reads are spread).
// sB[16][512][32]: lin1, row rp = wv*64+ti*16+lr = orig row; same granule XOR.
// sC[48][512]: lin2 rows (42 real + 6 zero); granule g' = g ^ (row&7).
// w_ssn[512][64]: n-gate input-side ss weights (kept in VGPRs by mega6).
// w_ih512b, bias_comb: preamble GEMM (gi_base).
__global__ __launch_bounds__(256) void prep3_kernel(
    const float* __restrict__ w_ih, const float* __restrict__ w_hh,
    const float* __restrict__ lin1_w, const float* __restrict__ lin2_w,
    const float* __restrict__ b_ih, const float* __restrict__ b_hh,
    bf16_t* __restrict__ sA, bf16_t* __restrict__ sB, bf16_t* __restrict__ sC,
    bf16_t* __restrict__ w_ssn, bf16_t* __restrict__ w_ih512b,
    float* __restrict__ bias_comb){
  const int NA = 36*24576, NB2 = 16*16384, NC2 = 24576, NS = 512*64, NI = G3*512;
  const int total = NA+NB2+NC2+NS+NI+G3;
  for (int idx = blockIdx.x*256 + threadIdx.x; idx < total; idx += gridDim.x*256){
    int i = idx;
    if (i < NA){
      int c = i/24576, r2 = i%24576, rp = r2>>5, kk = r2&31, gq = kk>>3, e = kk&7;
      int k0 = c>>1, tig = c&1;
      int wv = rp/96, rem = rp%96, g = rem>>5, rr = rem&31, l2 = rr>>4, lr = rr&15;
      int half = gq ^ (lr&3);
      int orow = g*512 + wv*64 + (tig*2+l2)*16 + lr;
      int kcol = k0*32 + half*8 + e;
      float v = (kcol < 512) ? w_hh[orow*512 + kcol]
              : ((kcol < 512+OUTSZ && orow < 1024) ? w_ih[(size_t)orow*LDIH + kcol] : 0.f);
      sA[i] = __float2bfloat16(v);
    } else if ((i -= NA) < NB2){
      int c = i/16384, r2 = i%16384, rp = r2>>5, kk = r2&31, gq = kk>>3, e = kk&7;
      int half = gq ^ (rp&3);
      sB[i] = __float2bfloat16(lin1_w[rp*512 + c*32 + half*8 + e]);
    } else if ((i -= NB2) < NC2){
      int j = i>>9, r = i&511, gq = r>>3, e = r&7;
      int g = gq ^ (j&7);
      float v = (j < OUTSZ) ? lin2_w[j*512 + g*8 + e] : 0.f;
      sC[i] = __float2bfloat16(v);
    } else if ((i -= NC2) < NS){
      int j = i>>6, k = i&63;
      float v = (k < OUTSZ) ? w_ih[(size_t)(1024+j)*LDIH + 512 + k] : 0.f;
      w_ssn[i] = __float2bfloat16(v);
    } else if ((i -= NS) < NI){
      int r = i>>9, c = i&511;
      w_ih512b[i] = __float2bfloat16(w_ih[(size_t)r*LDIH + c]);
    } else {
      int j = i - NI;
      bias_comb[j] = b_ih[j] + (j < 1024 ? b_hh[j] : 0.f);
    }
  }
}

// ---------------- attention precompute (step-invariant) ----------------
__global__ __launch_bounds__(256) void att_kernel(const float* __restrict__ feat,
                                                  const float* __restrict__ att_w,
                                                  bf16_t* __restrict__ att_feat){
  int b = blockIdx.x;
  const float* fb = feat + (size_t)b * FEAT * HW;
  __shared__ float part[4][64];
  __shared__ float attv[64];
  int t = threadIdx.x;
  int s = t & 63, q = t >> 6;
  float acc = 0.f;
  for (int c = q*128; c < q*128 + 128; ++c)
    acc = fmaf(fb[c*HW + s], att_w[c], acc);
  part[q][s] = acc;
  __syncthreads();
  if (t < 64){
    float v = part[0][t] + part[1][t] + part[2][t] + part[3][t];
    float m = v;
    for (int o = 32; o > 0; o >>= 1) m = fmaxf(m, __shfl_xor(m, o));
    float e = __expf(v - m);
    float ssum = e;
    for (int o = 32; o > 0; o >>= 1) ssum += __shfl_xor(ssum, o);
    attv[t] = e / ssum * 2.0f;   // * BETA
  }
  __syncthreads();
  for (int c = t; c < FEAT; c += 256){
    const float4* row = (const float4*)(fb + c*HW);
    float a2 = 0.f;
    #pragma unroll
    for (int k = 0; k < 16; ++k){
      float4 v4 = row[k];
      a2 = fmaf(v4.x, attv[k*4+0], a2);
      a2 = fmaf(v4.y, attv[k*4+1], a2);
      a2 = fmaf(v4.z, attv[k*4+2], a2);
      a2 = fmaf(v4.w, attv[k*4+3], a2);
    }
    att_feat[(size_t)b*FEAT + c] = __float2bfloat16(a2);
  }
}

// ---------------- bf16 MFMA GEMM (NT) for gi_base preamble ----------------
__global__ __launch_bounds__(256) void gemm_mfma(const bf16_t* __restrict__ A,
                                                 const bf16_t* __restrict__ W,
                                                 const float* __restrict__ bias,
                                                 float* __restrict__ C,
                                                 int K, int lda, int ldw, int ldc){
  const int tid = threadIdx.x;
  const int w = tid >> 6, lane = tid & 63;
  const int r = lane & 15, half = lane >> 4;
  const int m_base = blockIdx.y * 64;
  const int n_base = blockIdx.x * 64 + w * 16;
  const bf16_t* Ap = A + (size_t)(m_base + r)*lda + half*8;
  const bf16_t* Wp = W + (size_t)(n_base + r)*ldw + half*8;
  f32x4 acc[4] = {};
  for (int k0 = 0; k0 < K; k0 += 32){
    bf16x8 bfrag = *(const bf16x8*)(Wp + k0);
    #pragma unroll
    for (int i = 0; i < 4; ++i){
      bf16x8 afrag = *(const bf16x8*)(Ap + (size_t)i*16*lda + k0);
      acc[i] = MFMA(afrag, bfrag, acc[i]);
    }
  }
  const float bv = bias ? bias[n_base + r] : 0.f;
  #pragma unroll
  for (int i = 0; i < 4; ++i)
    #pragma unroll
    for (int q = 0; q < 4; ++q)
      C[(size_t)(m_base + i*16 + half*4 + q)*ldc + n_base + r] = acc[i][q] + bv;
}

// ---------------- the 32-step scan with LDS-staged weight pipeline ----------------
// 128 blocks x 512 threads (8 waves). Wave wv owns h-cols [wv*64, wv*64+64).
// 53 chunks/step through a 2-slot 48KB LDS ring: vmcnt(counted) -> barrier ->
// ds_read+MFMA -> barrier -> issue(c+2). Chained across phases AND steps.
__global__ __launch_bounds__(512, 2) void mega6_kernel(
    const float* __restrict__ gi_base,
    const bf16_t* __restrict__ sA,
    const bf16_t* __restrict__ sB,
    const bf16_t* __restrict__ sC,
    const bf16_t* __restrict__ w_ssn,
    const float* __restrict__ lin1_b,
    const float* __restrict__ lin2_b,
    const float* __restrict__ b_hh,
    const float* __restrict__ gt,
    const int* __restrict__ line_prob,
    const float* __restrict__ sample_prob,
    float* __restrict__ out){
  __shared__ bf16_t ring[2][24576];      // 2 x 48KB
  __shared__ bf16_t lds_x[MB][LDX];      // [h(512) | ss(42) | zeros]
  __shared__ bf16_t o1s[MB][LDH];
  const int tid = threadIdx.x;
  const int wv = tid >> 6, l = tid & 63;
  const int lr = l & 15, half = l >> 4;
  const int m0 = blockIdx.x * MB;
  const int colbase = wv * 64;
  const int swz8 = (half ^ (lr & 3)) * 8;      // staged-granule XOR (bf16 units)

  // zero lds_x (h=0, ss=0 at t=0)
  for (int i = tid; i < MB*LDX/2; i += 512) ((uint32_t*)lds_x)[i] = 0u;

  // persistent per-lane constants
  float bhn[4], lb1[4];
  #pragma unroll
  for (int ti = 0; ti < 4; ++ti){
    bhn[ti] = b_hh[1024 + colbase + ti*16 + lr];
    lb1[ti] = lin1_b[colbase + ti*16 + lr];
  }
  const int j3 = wv*16 + lr;
  const float b2c = (wv < 3 && j3 < OUTSZ) ? lin2_b[j3] : 0.f;
  // ssn weights persistent in VGPRs (32 regs)
  bf16x8 sfr[4][2];
  #pragma unroll
  for (int ti = 0; ti < 4; ++ti)
    #pragma unroll
    for (int ks = 0; ks < 2; ++ks)
      sfr[ti][ks] = *(const bf16x8*)(w_ssn + (size_t)(colbase + ti*16 + lr)*64 + ks*32 + half*8);

  float hp[4][4] = {};

  auto issue = [&](int t2, int c2){
    if (t2 >= NL) return;
    const bf16_t* src; int n;
    if (c2 < 36){ src = sA + (size_t)c2*24576; n = 6; }
    else if (c2 < 52){ src = sB + (size_t)(c2-36)*16384; n = 4; }
    else { src = sC; n = 6; }
    bf16_t* dst = ring[(t2 + c2) & 1];
    for (int i = 0; i < n; ++i)
      gld16(src + tid*8 + i*4096, dst + tid*8 + i*4096);
  };

  __syncthreads();
  issue(0, 0); issue(0, 1);

  for (int t = 0; t < NL; ++t){
    const int s_ev = t & 1;
    bf16_t* Rev = ring[s_ev];
    bf16_t* Rod = ring[s_ev ^ 1];

    // ================= phase A: ghss over 36 staged chunks =================
    f32x4 accA[3][4] = {};
    #pragma unroll 1
    for (int k0 = 0; k0 < 18; ++k0){
      // even chunk (tig=0)
      WAITV(6); __syncthreads();
      {
        bf16x8 a = *(const bf16x8*)&lds_x[lr][k0*32 + half*8];
        #pragma unroll
        for (int g = 0; g < 3; ++g)
          #pragma unroll
          for (int l2 = 0; l2 < 2; ++l2){
            int rp = wv*96 + g*32 + l2*16 + lr;
            bf16x8 bf = *(const bf16x8*)&Rev[rp*32 + swz8];
            accA[g][l2] = MFMA(a, bf, accA[g][l2]);
          }
      }
      __syncthreads();
      issue(t, 2*k0 + 2);
      // odd chunk (tig=1)
      if (k0 < 17) { WAITV(6); } else { WAITV(4); }
      __syncthreads();
      {
        bf16x8 a = *(const bf16x8*)&lds_x[lr][k0*32 + half*8];
        #pragma unroll
        for (int g = 0; g < 3; ++g)
          #pragma unroll
          for (int l2 = 0; l2 < 2; ++l2){
            int rp = wv*96 + g*32 + l2*16 + lr;
            bf16x8 bf = *(const bf16x8*)&Rod[rp*32 + swz8];
            accA[g][2 + l2] = MFMA(a, bf, accA[g][2 + l2]);
          }
      }
      __syncthreads();
      issue(t, 2*k0 + 3);
    }

    // ---- ssn: input-side ss contribution to n gate (weights in VGPRs) ----
    f32x4 accS[4] = {};
    #pragma unroll
    for (int ks = 0; ks < 2; ++ks){
      bf16x8 a2 = *(const bf16x8*)&lds_x[lr][512 + ks*32 + half*8];
      #pragma unroll
      for (int ti = 0; ti < 4; ++ti)
        accS[ti] = MFMA(a2, sfr[ti][ks], accS[ti]);
    }

    // ---- gates (gi_base slice read per step; L2-resident, hidden by pipeline) ----
    #pragma unroll
    for (int ti = 0; ti < 4; ++ti)
      #pragma unroll
      for (int q = 0; q < 4; ++q){
        const float* gp = gi_base + (size_t)(m0 + half*4 + q)*G3 + colbase + ti*16 + lr;
        float ir = accA[0][ti][q] + gp[0];
        float iz = accA[1][ti][q] + gp[512];
        float hn = accA[2][ti][q] + bhn[ti];
        float gn = gp[1024] + accS[ti][q];
        float r = sigmoidf_(ir);
        float z = sigmoidf_(iz);
        float n = tanhf(gn + r*hn);
        float hv = (1.f - z)*n + z*hp[ti][q];
        hp[ti][q] = hv;
        lds_x[half*4 + q][colbase + ti*16 + lr] = __float2bfloat16(hv);
      }

    // ================= phase B: lin1 over 16 staged chunks =================
    f32x4 accB[4] = {};
    #pragma unroll 1
    for (int cb = 0; cb < 16; ++cb){
      if (cb < 15) { WAITV(4); } else { WAITV(6); }
      __syncthreads();
      {
        bf16_t* R = ring[(t + cb) & 1];
        union { u16x8 u; bf16x8 b; } va;
        va.u = *(const u16x8*)&lds_x[lr][cb*32 + half*8];
        #pragma unroll
        for (int e = 0; e < 8; ++e)
          if (va.u[e] & 0x8000) va.u[e] = 0;       // relu on bf16 sign bit
        #pragma unroll
        for (int ti = 0; ti < 4; ++ti){
          int rp = wv*64 + ti*16 + lr;
          bf16x8 bf = *(const bf16x8*)&R[rp*32 + swz8];
          accB[ti] = MFMA(va.b, bf, accB[ti]);
        }
      }
      __syncthreads();
      int nc = 38 + cb;
      if (nc < 53) issue(t, nc); else issue(t + 1, 0);
    }
    // o1 -> LDS (bias + relu)
    #pragma unroll
    for (int ti = 0; ti < 4; ++ti)
      #pragma unroll
      for (int q = 0; q < 4; ++q)
        o1s[half*4 + q][colbase + ti*16 + lr] =
            __float2bfloat16(fmaxf(accB[ti][q] + lb1[ti], 0.f));

    // ================= phase C: lin2 (staged chunk) + outputs + ss_{t+1} =================
    if (t < NL-1) { WAITV(6); } else { WAITV(0); }
    __syncthreads();
    if (wv < 3){
      f32x4 accC = {};
      #pragma unroll 4
      for (int k0 = 0; k0 < 16; ++k0){
        bf16x8 a = *(const bf16x8*)&o1s[lr][k0*32 + half*8];
        int g = k0*4 + half;
        bf16x8 bf = *(const bf16x8*)&Rev[j3*512 + ((g ^ (j3 & 7)) << 3)];
        accC = MFMA(a, bf, accC);
      }
      #pragma unroll
      for (int q = 0; q < 4; ++q){
        float val = accC[q] + b2c;
        int row = half*4 + q;
        int bm = m0 + row;
        if (j3 < 40){
          out[((size_t)bm*NL + t)*40 + j3] = val;
        } else if (j3 < 42){
          float other = __shfl_xor(val, 1);
          float mx = fmaxf(val, other);
          float e0 = __expf(val - mx), e1 = __expf(other - mx);
          out[(size_t)B*NL*40 + ((size_t)bm*NL + t)*2 + (j3 - 40)] = e0/(e0 + e1);
        }
        if (t + 1 < NL && j3 < OUTSZ){
          bool up = sample_prob[(size_t)(t+1)*B + bm] < 0.1f;
          float gtv;
          if (j3 < 40) gtv = gt[((size_t)bm*NL + t)*40 + j3];
          else {
            float pv = (float)line_prob[bm*NL + t];
            gtv = (j3 == 40) ? 1.f - pv : pv;
          }
          lds_x[row][512 + j3] = __float2bfloat16(up ? val : gtv);
        }
      }
    }
    __syncthreads();     // C chunk reads + ss writes done
    issue(t + 1, 1);     // into the slot C just freed
  }
}

extern "C" void kernel_launch(void* const* d_in, const int* in_sizes, int n_in,
                              void* d_out, int out_size, void* d_ws, size_t ws_size,
                              hipStream_t stream) {
  const float* img         = (const float*)d_in[0];
  const float* gt          = (const float*)d_in[1];
  const int*   line_prob   = (const int*)d_in[2];
  const float* sample_prob = (const float*)d_in[3];
  const float* att_w       = (const float*)d_in[4];
  // d_in[5] att_b: unused — softmax shift-invariance cancels it
  const float* w_ih        = (const float*)d_in[6];
  const float* w_hh        = (const float*)d_in[7];
  const float* b_ih        = (const float*)d_in[8];
  const float* b_hh        = (const float*)d_in[9];
  const float* lin1_w      = (const float*)d_in[10];
  const float* lin1_b      = (const float*)d_in[11];
  const float* lin2_w      = (const float*)d_in[12];
  const float* lin2_b      = (const float*)d_in[13];
  float* out = (float*)d_out;

  char* p = (char*)d_ws;
  auto alloc = [&](size_t bytes){ void* q = p; p += (bytes + 255) & ~(size_t)255; return q; };
  float*  gi_base   = (float*)alloc((size_t)B*G3*4);
  bf16_t* att_bf    = (bf16_t*)alloc((size_t)B*FEAT*2);
  bf16_t* sA        = (bf16_t*)alloc((size_t)36*24576*2);
  bf16_t* sB        = (bf16_t*)alloc((size_t)16*16384*2);
  bf16_t* sC        = (bf16_t*)alloc((size_t)24576*2);
  bf16_t* w_ssn     = (bf16_t*)alloc((size_t)512*64*2);
  bf16_t* w_ih512b  = (bf16_t*)alloc((size_t)G3*512*2);
  float*  bias_comb = (float*)alloc((size_t)G3*4);

  prep3_kernel<<<4096, 256, 0, stream>>>(w_ih, w_hh, lin1_w, lin2_w, b_ih, b_hh,
                                         sA, sB, sC, w_ssn, w_ih512b, bias_comb);
  att_kernel<<<B, 256, 0, stream>>>(img, att_w, att_bf);
  // gi_base = att_feat @ W_ih[:, :512]^T + b_ih + (b_hh for r/z)   (step-invariant)
  gemm_mfma<<<dim3(G3/64, B/64), 256, 0, stream>>>(att_bf, w_ih512b, bias_comb, gi_base,
                                                   512, 512, 512, G3);
  mega6_kernel<<<NBLK, 512, 0, stream>>>(gi_base, sA, sB, sC, w_ssn, lin1_b, lin2_b,
                                         b_hh, gt, line_prob, sample_prob, out);
}

// Round 10
// 1462.874 us; speedup vs baseline: 5.6995x; 1.2656x over previous
//
#include <hip/hip_runtime.h>
#include <hip/hip_bf16.h>
#include <cstdint>

#define B 2048
#define NL 32
#define FEAT 512
#define HID 512
#define HW 64
#define OUTSZ 42
#define G3 1536
#define LDIH 554   // gru_w_ih row stride
#define MB 16      // batch rows per block
#define NBLK (B/MB)   // 128
#define LDX 584    // lds_x row stride
#define LDH 520    // o1s row stride
#define CPS 72     // chunks per step: 54 A + 16 B + 2 C
#define CHW 16384  // bf16 elements per 32KB chunk

typedef __bf16 bf16x8 __attribute__((ext_vector_type(8)));
typedef unsigned short u16x8 __attribute__((ext_vector_type(8)));
typedef float f32x4 __attribute__((ext_vector_type(4)));
typedef __hip_bfloat16 bf16_t;

#define MFMA(a,b,c) __builtin_amdgcn_mfma_f32_16x16x32_bf16(a,b,c,0,0,0)
#define WAITV(n) asm volatile("s_waitcnt vmcnt(" #n ")" ::: "memory")

static __device__ __forceinline__ float sigmoidf_(float x){ return 1.f/(1.f+__expf(-x)); }

static __device__ __forceinline__ void gld16(const bf16_t* g, bf16_t* l){
  __builtin_amdgcn_global_load_lds(
      (const __attribute__((address_space(1))) void*)g,
      (__attribute__((address_space(3))) void*)l, 16, 0, 0);
}

// ---------------- one-time weight prep into STAGING layouts ----------------
// All staged chunks are 32KB. Granule swizzle: storage granule gq of row rp
// holds k-quarter half = gq ^ ((rp>>1)&3)  -> wave-wide conflict-free ds_read_b128.
// sA[54][512][32]: chunk (k0,g), row rp = gate-block row, k = k0*32+half*8+e.
// sB[16][512][32]: lin1, chunk k0, row rp = lin1 row.
// sC[2][64][256]: lin2 k-halves; row j (42 real), granule s holds g = s^(j&7),
//   k = n*256 + g*8 + e.
// w_ssn[512][64]; w_ih512b, bias_comb: preamble GEMM.
__global__ __launch_bounds__(256) void prep4_kernel(
    const float* __restrict__ w_ih, const float* __restrict__ w_hh,
    const float* __restrict__ lin1_w, const float* __restrict__ lin2_w,
    const float* __restrict__ b_ih, const float* __restrict__ b_hh,
    bf16_t* __restrict__ sA, bf16_t* __restrict__ sB, bf16_t* __restrict__ sC,
    bf16_t* __restrict__ w_ssn, bf16_t* __restrict__ w_ih512b,
    float* __restrict__ bias_comb){
  const int NA = 54*CHW, NB2 = 16*CHW, NC2 = 2*CHW, NS = 512*64, NI = G3*512;
  const int total = NA+NB2+NC2+NS+NI+G3;
  for (int idx = blockIdx.x*256 + threadIdx.x; idx < total; idx += gridDim.x*256){
    int i = idx;
    if (i < NA){
      int c = i/CHW, r2 = i%CHW, rp = r2>>5, kk = r2&31, gq = kk>>3, e = kk&7;
      int k0 = c/3, g = c%3;
      int half = gq ^ ((rp>>1)&3);
      int orow = g*512 + rp;
      int k = k0*32 + half*8 + e;
      float v = (k < 512) ? w_hh[orow*512 + k]
              : ((k < 512+OUTSZ && g < 2) ? w_ih[(size_t)orow*LDIH + k] : 0.f);
      sA[i] = __float2bfloat16(v);
    } else if ((i -= NA) < NB2){
      int c = i/CHW, r2 = i%CHW, rp = r2>>5, kk = r2&31, gq = kk>>3, e = kk&7;
      int half = gq ^ ((rp>>1)&3);
      sB[i] = __float2bfloat16(lin1_w[rp*512 + c*32 + half*8 + e]);
    } else if ((i -= NB2) < NC2){
      int n = i/CHW, r2 = i%CHW, j = r2>>8, kk = r2&255, s = kk>>3, e = kk&7;
      int g = s ^ (j & 7);
      int k = n*256 + g*8 + e;
      float v = (j < OUTSZ) ? lin2_w[j*512 + k] : 0.f;
      sC[i] = __float2bfloat16(v);
    } else if ((i -= NC2) < NS){
      int j = i>>6, k = i&63;
      float v = (k < OUTSZ) ? w_ih[(size_t)(1024+j)*LDIH + 512 + k] : 0.f;
      w_ssn[i] = __float2bfloat16(v);
    } else if ((i -= NS) < NI){
      int r = i>>9, c = i&511;
      w_ih512b[i] = __float2bfloat16(w_ih[(size_t)r*LDIH + c]);
    } else {
      int j = i - NI;
      bias_comb[j] = b_ih[j] + (j < 1024 ? b_hh[j] : 0.f);
    }
  }
}

// ---------------- attention precompute (step-invariant) ----------------
__global__ __launch_bounds__(256) void att_kernel(const float* __restrict__ feat,
                                                  const float* __restrict__ att_w,
                                                  bf16_t* __restrict__ att_feat){
  int b = blockIdx.x;
  const float* fb = feat + (size_t)b * FEAT * HW;
  __shared__ float part[4][64];
  __shared__ float attv[64];
  int t = threadIdx.x;
  int s = t & 63, q = t >> 6;
  float acc = 0.f;
  for (int c = q*128; c < q*128 + 128; ++c)
    acc = fmaf(fb[c*HW + s], att_w[c], acc);
  part[q][s] = acc;
  __syncthreads();
  if (t < 64){
    float v = part[0][t] + part[1][t] + part[2][t] + part[3][t];
    float m = v;
    for (int o = 32; o > 0; o >>= 1) m = fmaxf(m, __shfl_xor(m, o));
    float e = __expf(v - m);
    float ssum = e;
    for (int o = 32; o > 0; o >>= 1) ssum += __shfl_xor(ssum, o);
    attv[t] = e / ssum * 2.0f;   // * BETA
  }
  __syncthreads();
  for (int c = t; c < FEAT; c += 256){
    const float4* row = (const float4*)(fb + c*HW);
    float a2 = 0.f;
    #pragma unroll
    for (int k = 0; k < 16; ++k){
      float4 v4 = row[k];
      a2 = fmaf(v4.x, attv[k*4+0], a2);
      a2 = fmaf(v4.y, attv[k*4+1], a2);
      a2 = fmaf(v4.z, attv[k*4+2], a2);
      a2 = fmaf(v4.w, attv[k*4+3], a2);
    }
    att_feat[(size_t)b*FEAT + c] = __float2bfloat16(a2);
  }
}

// ---------------- bf16 MFMA GEMM (NT) for gi_base preamble ----------------
__global__ __launch_bounds__(256) void gemm_mfma(const bf16_t* __restrict__ A,
                                                 const bf16_t* __restrict__ W,
                                                 const float* __restrict__ bias,
                                                 float* __restrict__ C,
                                                 int K, int lda, int ldw, int ldc){
  const int tid = threadIdx.x;
  const int w = tid >> 6, lane = tid & 63;
  const int r = lane & 15, half = lane >> 4;
  const int m_base = blockIdx.y * 64;
  const int n_base = blockIdx.x * 64 + w * 16;
  const bf16_t* Ap = A + (size_t)(m_base + r)*lda + half*8;
  const bf16_t* Wp = W + (size_t)(n_base + r)*ldw + half*8;
  f32x4 acc[4] = {};
  for (int k0 = 0; k0 < K; k0 += 32){
    bf16x8 bfrag = *(const bf16x8*)(Wp + k0);
    #pragma unroll
    for (int i = 0; i < 4; ++i){
      bf16x8 afrag = *(const bf16x8*)(Ap + (size_t)i*16*lda + k0);
      acc[i] = MFMA(afrag, bfrag, acc[i]);
    }
  }
  const float bv = bias ? bias[n_base + r] : 0.f;
  #pragma unroll
  for (int i = 0; i < 4; ++i)
    #pragma unroll
    for (int q = 0; q < 4; ++q)
      C[(size_t)(m_base + i*16 + half*4 + q)*ldc + n_base + r] = acc[i][q] + bv;
}

// ---------------- the 32-step scan: uniform 32KB chunks, 3-slot ring ----------------
// 128 blocks x 512 threads (8 waves). Per chunk: WAITV(4) -> barrier ->
// ds_read+MFMA -> issue(c+2). 72 chunks/step, 1 barrier each. Conflict-free
// staged reads via the ((rp>>1)&3) granule swizzle. gi_base in registers.
__global__ __launch_bounds__(512, 2) void mega7_kernel(
    const float* __restrict__ gi_base,
    const bf16_t* __restrict__ sA,
    const bf16_t* __restrict__ sB,
    const bf16_t* __restrict__ sC,
    const bf16_t* __restrict__ w_ssn,
    const float* __restrict__ lin1_b,
    const float* __restrict__ lin2_b,
    const float* __restrict__ b_hh,
    const float* __restrict__ gt,
    const int* __restrict__ line_prob,
    const float* __restrict__ sample_prob,
    float* __restrict__ out){
  __shared__ bf16_t ring[3*CHW];         // 3 x 32KB
  __shared__ bf16_t lds_x[MB][LDX];      // [h(512) | ss(42) | zeros]
  __shared__ bf16_t o1s[MB][LDH];
  const int tid = threadIdx.x;
  const int wv = tid >> 6, l = tid & 63;
  const int lr = l & 15, half = l >> 4;
  const int m0 = blockIdx.x * MB;
  const int colbase = wv * 64;
  // staged-read offsets (conflict-free swizzle)
  const int rowoff = (colbase + lr)*32 + (half ^ ((lr >> 1) & 3))*8;

  for (int i = tid; i < MB*LDX/2; i += 512) ((uint32_t*)lds_x)[i] = 0u;

  // ---- register-resident gi_base slice: 4(ti) x 4(q) x 3 gates ----
  float gir[4][4], giz[4][4], gin_[4][4];
  #pragma unroll
  for (int ti = 0; ti < 4; ++ti)
    #pragma unroll
    for (int q = 0; q < 4; ++q){
      const float* gp = gi_base + (size_t)(m0 + half*4 + q)*G3 + colbase + ti*16 + lr;
      gir[ti][q]  = gp[0];
      giz[ti][q]  = gp[512];
      gin_[ti][q] = gp[1024];
    }
  float bhn[4], lb1[4];
  #pragma unroll
  for (int ti = 0; ti < 4; ++ti){
    bhn[ti] = b_hh[1024 + colbase + ti*16 + lr];
    lb1[ti] = lin1_b[colbase + ti*16 + lr];
  }
  const int j3 = wv*16 + lr;
  const float b2c = (wv < 3 && j3 < OUTSZ) ? lin2_b[j3] : 0.f;
  // ssn weights persistent in VGPRs
  bf16x8 sfr[4][2];
  #pragma unroll
  for (int ti = 0; ti < 4; ++ti)
    #pragma unroll
    for (int ks = 0; ks < 2; ++ks)
      sfr[ti][ks] = *(const bf16x8*)(w_ssn + (size_t)(colbase + ti*16 + lr)*64 + ks*32 + half*8);

  float hp[4][4] = {};

  auto issue = [&](uint32_t g){
    const bf16_t* src = sA;              // dummy tail issues read sA
    if (g < (uint32_t)NL*CPS){
      uint32_t c = g % CPS;
      src = (c < 54) ? sA + (size_t)c*CHW
          : (c < 70) ? sB + (size_t)(c-54)*CHW
                     : sC + (size_t)(c-70)*CHW;
    }
    bf16_t* dst = ring + (g % 3)*CHW;
    #pragma unroll
    for (int i = 0; i < 4; ++i)
      gld16(src + tid*8 + i*4096, dst + tid*8 + i*4096);
  };

  uint32_t gc = 0;
  issue(0); issue(1);

  for (int t = 0; t < NL; ++t){
    // ================= phase A: 54 chunks (k0-major, gate-minor) =================
    f32x4 accA[3][4] = {};
    #pragma unroll 1
    for (int k0 = 0; k0 < 18; ++k0){
      bf16x8 a;
      #pragma unroll
      for (int g = 0; g < 3; ++g){
        WAITV(4);
        __syncthreads();
        a = *(const bf16x8*)&lds_x[lr][k0*32 + half*8];
        const bf16_t* S = ring + (gc % 3)*CHW;
        #pragma unroll
        for (int ti = 0; ti < 4; ++ti){
          bf16x8 bf = *(const bf16x8*)&S[rowoff + ti*512];
          accA[g][ti] = MFMA(a, bf, accA[g][ti]);
        }
        issue(gc + 2); ++gc;
      }
    }

    // ---- ssn (weights in VGPRs) ----
    f32x4 accS[4] = {};
    #pragma unroll
    for (int ks = 0; ks < 2; ++ks){
      bf16x8 a2 = *(const bf16x8*)&lds_x[lr][512 + ks*32 + half*8];
      #pragma unroll
      for (int ti = 0; ti < 4; ++ti)
        accS[ti] = MFMA(a2, sfr[ti][ks], accS[ti]);
    }

    // ---- gates (h-col reads all completed by chunk 47; 6 barriers ago) ----
    #pragma unroll
    for (int ti = 0; ti < 4; ++ti)
      #pragma unroll
      for (int q = 0; q < 4; ++q){
        float ir = accA[0][ti][q] + gir[ti][q];
        float iz = accA[1][ti][q] + giz[ti][q];
        float hn = accA[2][ti][q] + bhn[ti];
        float gn = gin_[ti][q] + accS[ti][q];
        float r = sigmoidf_(ir);
        float z = sigmoidf_(iz);
        float n = tanhf(gn + r*hn);
        float hv = (1.f - z)*n + z*hp[ti][q];
        hp[ti][q] = hv;
        lds_x[half*4 + q][colbase + ti*16 + lr] = __float2bfloat16(hv);
      }

    // ================= phase B: 16 chunks (lin1) =================
    f32x4 accB[4] = {};
    #pragma unroll 1
    for (int k0 = 0; k0 < 16; ++k0){
      WAITV(4);
      __syncthreads();
      union { u16x8 u; bf16x8 b; } va;
      va.u = *(const u16x8*)&lds_x[lr][k0*32 + half*8];
      #pragma unroll
      for (int e = 0; e < 8; ++e)
        if (va.u[e] & 0x8000) va.u[e] = 0;       // relu on bf16
      const bf16_t* S = ring + (gc % 3)*CHW;
      #pragma unroll
      for (int ti = 0; ti < 4; ++ti){
        bf16x8 bf = *(const bf16x8*)&S[rowoff + ti*512];
        accB[ti] = MFMA(va.b, bf, accB[ti]);
      }
      issue(gc + 2); ++gc;
    }
    #pragma unroll
    for (int ti = 0; ti < 4; ++ti)
      #pragma unroll
      for (int q = 0; q < 4; ++q)
        o1s[half*4 + q][colbase + ti*16 + lr] =
            __float2bfloat16(fmaxf(accB[ti][q] + lb1[ti], 0.f));

    // ================= phase C: 2 chunks (lin2) =================
    f32x4 accC = {};
    #pragma unroll
    for (int n = 0; n < 2; ++n){
      WAITV(4);
      __syncthreads();
      if (wv < 3){
        const bf16_t* S = ring + (gc % 3)*CHW;
        #pragma unroll
        for (int k0 = 0; k0 < 8; ++k0){
          bf16x8 a = *(const bf16x8*)&o1s[lr][(n*8 + k0)*32 + half*8];
          int sg = (k0*4 + half) ^ (j3 & 7);
          bf16x8 bf = *(const bf16x8*)&S[j3*256 + sg*8];
          accC = MFMA(a, bf, accC);
        }
      }
      issue(gc + 2); ++gc;
    }
    // outputs + ss_{t+1}  (next read of these LDS cols is ≥14 barriers away)
    if (wv < 3){
      #pragma unroll
      for (int q = 0; q < 4; ++q){
        float val = accC[q] + b2c;
        int row = half*4 + q;
        int bm = m0 + row;
        if (j3 < 40){
          out[((size_t)bm*NL + t)*40 + j3] = val;
        } else if (j3 < 42){
          float other = __shfl_xor(val, 1);
          float mx = fmaxf(val, other);
          float e0 = __expf(val - mx), e1 = __expf(other - mx);
          out[(size_t)B*NL*40 + ((size_t)bm*NL + t)*2 + (j3 - 40)] = e0/(e0 + e1);
        }
        if (t + 1 < NL && j3 < OUTSZ){
          bool up = sample_prob[(size_t)(t+1)*B + bm] < 0.1f;
          float gtv;
          if (j3 < 40) gtv = gt[((size_t)bm*NL + t)*40 + j3];
          else {
            float pv = (float)line_prob[bm*NL + t];
            gtv = (j3 == 40) ? 1.f - pv : pv;
          }
          lds_x[row][512 + j3] = __float2bfloat16(up ? val : gtv);
        }
      }
    }
  }
}

extern "C" void kernel_launch(void* const* d_in, const int* in_sizes, int n_in,
                              void* d_out, int out_size, void* d_ws, size_t ws_size,
                              hipStream_t stream) {
  const float* img         = (const float*)d_in[0];
  const float* gt          = (const float*)d_in[1];
  const int*   line_prob   = (const int*)d_in[2];
  const float* sample_prob = (const float*)d_in[3];
  const float* att_w       = (const float*)d_in[4];
  // d_in[5] att_b: unused — softmax shift-invariance cancels it
  const float* w_ih        = (const float*)d_in[6];
  const float* w_hh        = (const float*)d_in[7];
  const float* b_ih        = (const float*)d_in[8];
  const float* b_hh        = (const float*)d_in[9];
  const float* lin1_w      = (const float*)d_in[10];
  const float* lin1_b      = (const float*)d_in[11];
  const float* lin2_w      = (const float*)d_in[12];
  const float* lin2_b      = (const float*)d_in[13];
  float* out = (float*)d_out;

  char* p = (char*)d_ws;
  auto alloc = [&](size_t bytes){ void* q = p; p += (bytes + 255) & ~(size_t)255; return q; };
  float*  gi_base   = (float*)alloc((size_t)B*G3*4);
  bf16_t* att_bf    = (bf16_t*)alloc((size_t)B*FEAT*2);
  bf16_t* sA        = (bf16_t*)alloc((size_t)54*CHW*2);
  bf16_t* sB        = (bf16_t*)alloc((size_t)16*CHW*2);
  bf16_t* sC        = (bf16_t*)alloc((size_t)2*CHW*2);
  bf16_t* w_ssn     = (bf16_t*)alloc((size_t)512*64*2);
  bf16_t* w_ih512b  = (bf16_t*)alloc((size_t)G3*512*2);
  float*  bias_comb = (float*)alloc((size_t)G3*4);

  prep4_kernel<<<4096, 256, 0, stream>>>(w_ih, w_hh, lin1_w, lin2_w, b_ih, b_hh,
                                         sA, sB, sC, w_ssn, w_ih512b, bias_comb);
  att_kernel<<<B, 256, 0, stream>>>(img, att_w, att_bf);
  gemm_mfma<<<dim3(G3/64, B/64), 256, 0, stream>>>(att_bf, w_ih512b, bias_comb, gi_base,
                                                   512, 512, 512, G3);
  mega7_kernel<<<NBLK, 512, 0, stream>>>(gi_base, sA, sB, sC, w_ssn, lin1_b, lin2_b,
                                         b_hh, gt, line_prob, sample_prob, out);
}